// Round 11
// baseline (281.856 us; speedup 1.0000x reference)
//
#include <hip/hip_runtime.h>
#include <hip/hip_bf16.h>
#include <math.h>

#define TSTEPS 128
#define HD 16      // GRU hidden
#define G3 48      // 3*H gates
#define AD 32      // 2*H attention dim
#define CHUNK 8    // serial steps per gx-MFMA chunk
#define NCHK 16
#define RROW 18    // ring row halfs (16 + 2 pad -> conflict-free group reads)
#define RING_PW (4 * 3 * CHUNK * RROW)   // 1728 halfs per wave
#define SROW (TSTEPS * HD + 8)           // 2056 halfs per seq-dir history

#define SC1 1.44269504088896340736f   // log2(e)   : sigmoid prescale
#define SC2 2.88539008177792681472f   // 2*log2(e) : tanh prescale

typedef _Float16 h2 __attribute__((ext_vector_type(2)));
typedef _Float16 f16x8 __attribute__((ext_vector_type(8)));
typedef float f32x4 __attribute__((ext_vector_type(4)));

#if defined(__has_builtin)
#  if __has_builtin(__builtin_amdgcn_exp2f)
#    define EXP2F(x) __builtin_amdgcn_exp2f(x)
#  endif
#  if __has_builtin(__builtin_amdgcn_rcpf)
#    define RCPF(x) __builtin_amdgcn_rcpf(x)
#  endif
#endif
#ifndef EXP2F
#  define EXP2F(x) exp2f(x)
#endif
#ifndef RCPF
#  define RCPF(x) (1.0f / (x))
#endif

__device__ __forceinline__ float fdot2(h2 a, h2 b, float c) {
    return __builtin_amdgcn_fdot2(a, b, c, false);
}
// tanh(x) with pre-scaled input u = 2*log2e*x
__device__ __forceinline__ float tanh_pre(float u) {
    return 1.0f - 2.0f * RCPF(EXP2F(u) + 1.0f);
}

// Guarded row-major MFMA fragment load (k = k0+e, 0 beyond D), scaled.
template<int D>
__device__ __forceinline__ f16x8 load_frag(const float* __restrict__ rowptr,
                                           int k0, float scale) {
    f16x8 f;
    #pragma unroll
    for (int e = 0; e < 8; ++e) {
        const int k = k0 + e;
        f[e] = (k < D) ? (_Float16)(rowptr[k] * scale) : (_Float16)0.0f;
    }
    return f;
}

// One block = 128 threads = 2 waves = FOUR sequences (both GRU directions).
// Each wave runs 4 seq-dir chains: lane (g,u) owns h-unit u of seq-dir g and
// computes all three gates (24 fdot2 + 3 exp2 + 3 rcp) -- no cross-lane ops in
// the serial chain. gx = x @ Wih^T on the matrix pipe per 8-step chunk into a
// bank-tiled per-wave LDS ring (same-wave DS ordering -> barrier-free).
template<int D, bool HAS_PROJ>
__global__ __launch_bounds__(128, 2)
void gru_attn_kernel(
    const float* __restrict__ x,                      // [S, TSTEPS, D]
    const float* __restrict__ Wih_f, const float* __restrict__ Whh_f,
    const float* __restrict__ bih_f, const float* __restrict__ bhh_f,
    const float* __restrict__ Wih_b, const float* __restrict__ Whh_b,
    const float* __restrict__ bih_b, const float* __restrict__ bhh_b,
    const float* __restrict__ Wa, const float* __restrict__ ba,
    const float* __restrict__ ctxv,
    const float* __restrict__ Wm, const float* __restrict__ bm,
    float* __restrict__ out, int out_cols)
{
    __shared__ __align__(16) _Float16 ring[2 * RING_PW];   // 6912 B (+attn overlay)
    __shared__ __align__(16) _Float16 h1pool[8 * SROW];    // 32896 B

    const int tid  = threadIdx.x;
    const int lane = tid & 63;
    const int wv   = tid >> 6;
    const int g    = lane >> 4;          // seq-dir group within wave
    const int u    = lane & 15;          // h-unit / fragment row / col
    const int k0   = g * 8;              // fragment k base
    const int dir  = g >> 1;             // 0 = fwd, 1 = bwd
    const int sd   = wv * 4 + g;         // history row id (0..7)

    // ---- per-lane recurrent weights (prescaled) + biases ----
    const float* WhhP = dir ? Whh_b : Whh_f;
    const float* bihP = dir ? bih_b : bih_f;
    const float* bhhP = dir ? bhh_b : bhh_f;

    h2 wr_[8], wz_[8], wn_[8];
    {
        const float4* wrp = (const float4*)(WhhP + u * HD);
        const float4* wzp = (const float4*)(WhhP + (HD + u) * HD);
        const float4* wnp = (const float4*)(WhhP + (2 * HD + u) * HD);
        #pragma unroll
        for (int p = 0; p < 4; ++p) {
            const float4 a = wrp[p], b = wzp[p], cn = wnp[p];
            wr_[2*p]   = (h2){(_Float16)(a.x * SC1), (_Float16)(a.y * SC1)};
            wr_[2*p+1] = (h2){(_Float16)(a.z * SC1), (_Float16)(a.w * SC1)};
            wz_[2*p]   = (h2){(_Float16)(b.x * SC1), (_Float16)(b.y * SC1)};
            wz_[2*p+1] = (h2){(_Float16)(b.z * SC1), (_Float16)(b.w * SC1)};
            wn_[2*p]   = (h2){(_Float16)(cn.x * SC2), (_Float16)(cn.y * SC2)};
            wn_[2*p+1] = (h2){(_Float16)(cn.z * SC2), (_Float16)(cn.w * SC2)};
        }
    }
    const float brz = (bihP[u] + bhhP[u]) * SC1;                 // r combined
    const float bzz = (bihP[HD + u] + bhhP[HD + u]) * SC1;       // z combined
    const float bxn = bihP[2 * HD + u] * SC2;                    // n input-side
    const float bhn = bhhP[2 * HD + u] * SC2;                    // n hidden-side

    // ---- persistent B fragments (both dirs; all lanes serve both MFMAs) ----
    f16x8 bfragF[3], bfragB[3];
    #pragma unroll
    for (int n = 0; n < 3; ++n) {
        const float sc = (n < 2) ? SC1 : SC2;
        bfragF[n] = load_frag<D>(Wih_f + (16 * n + u) * D, k0, sc);
        bfragB[n] = load_frag<D>(Wih_b + (16 * n + u) * D, k0, sc);
    }

    // A-fragment source row: m-tile row fr=u -> seq-in-block wv*2+(u>>3), step u&7
    const size_t xstride = (size_t)TSTEPS * D;
    const float* xA0 = x + (size_t)(blockIdx.x * 4 + wv * 2 + (u >> 3)) * xstride;
    const int lsA = u & 7;

    _Float16* ringw = ring + wv * RING_PW;
    const _Float16* ringrd = ringw + (g * 3 * CHUNK) * RROW + u;
    _Float16* h1w = h1pool + sd * SROW + u;
    const _Float16* h1r = h1pool + sd * SROW;

    // ring-write lane constants: row = g*4+q -> gi=g>>1, ls2=(g&1)*4+q
    const int wls = (g & 1) * 4;
    const int ggF = (g >> 1);            // m=0 (fwd pair)
    const int ggB = 2 + (g >> 1);        // m=1 (bwd pair)

    float h_own = 0.0f;

    f16x8 afA = load_frag<D>(xA0 + (size_t)lsA * D, k0, 1.0f);                    // fwd, c=0
    f16x8 afB = load_frag<D>(xA0 + (size_t)(TSTEPS - 1 - lsA) * D, k0, 1.0f);     // bwd, c=0

    for (int c = 0; c < NCHK; ++c) {
        // ---- gx via MFMA -> ring ----
        #pragma unroll
        for (int n = 0; n < 3; ++n) {
            f32x4 a0 = {0.f, 0.f, 0.f, 0.f};
            a0 = __builtin_amdgcn_mfma_f32_16x16x32_f16(afA, bfragF[n], a0, 0, 0, 0);
            #pragma unroll
            for (int q = 0; q < 4; ++q)
                ringw[((ggF * 3 + n) * CHUNK + wls + q) * RROW + u] = (_Float16)a0[q];
            f32x4 a1 = {0.f, 0.f, 0.f, 0.f};
            a1 = __builtin_amdgcn_mfma_f32_16x16x32_f16(afB, bfragB[n], a1, 0, 0, 0);
            #pragma unroll
            for (int q = 0; q < 4; ++q)
                ringw[((ggB * 3 + n) * CHUNK + wls + q) * RROW + u] = (_Float16)a1[q];
        }
        // ---- prefetch next chunk's A fragments (hidden under serial steps) ----
        f16x8 afAn, afBn;
        if (c + 1 < NCHK) {
            const int s0 = (c + 1) * CHUNK + lsA;
            afAn = load_frag<D>(xA0 + (size_t)s0 * D, k0, 1.0f);
            afBn = load_frag<D>(xA0 + (size_t)(TSTEPS - 1 - s0) * D, k0, 1.0f);
        }

        // ---- serial 8 steps: all lanes active, 3 gates per lane, no shuffles ----
        #pragma unroll
        for (int ls = 0; ls < CHUNK; ++ls) {
            const float gxr = (float)ringrd[(0 * CHUNK + ls) * RROW];
            const float gxz = (float)ringrd[(1 * CHUNK + ls) * RROW];
            const float gxn = (float)ringrd[(2 * CHUNK + ls) * RROW] + bxn;

            float sr = brz, sr1 = 0.f, sz = bzz, sz1 = 0.f, sn = bhn, sn1 = 0.f;
            if (!(c == 0 && ls == 0)) {          // uniform branch (runtime only at ls==0)
                const f16x8* hp = (const f16x8*)(h1r + (c * CHUNK + ls - 1) * HD);
                const f16x8 hA = hp[0], hB = hp[1];
                sr  = fdot2(wr_[0], (h2){hA[0], hA[1]}, sr );
                sr1 = fdot2(wr_[1], (h2){hA[2], hA[3]}, sr1);
                sr  = fdot2(wr_[2], (h2){hA[4], hA[5]}, sr );
                sr1 = fdot2(wr_[3], (h2){hA[6], hA[7]}, sr1);
                sr  = fdot2(wr_[4], (h2){hB[0], hB[1]}, sr );
                sr1 = fdot2(wr_[5], (h2){hB[2], hB[3]}, sr1);
                sr  = fdot2(wr_[6], (h2){hB[4], hB[5]}, sr );
                sr1 = fdot2(wr_[7], (h2){hB[6], hB[7]}, sr1);
                sz  = fdot2(wz_[0], (h2){hA[0], hA[1]}, sz );
                sz1 = fdot2(wz_[1], (h2){hA[2], hA[3]}, sz1);
                sz  = fdot2(wz_[2], (h2){hA[4], hA[5]}, sz );
                sz1 = fdot2(wz_[3], (h2){hA[6], hA[7]}, sz1);
                sz  = fdot2(wz_[4], (h2){hB[0], hB[1]}, sz );
                sz1 = fdot2(wz_[5], (h2){hB[2], hB[3]}, sz1);
                sz  = fdot2(wz_[6], (h2){hB[4], hB[5]}, sz );
                sz1 = fdot2(wz_[7], (h2){hB[6], hB[7]}, sz1);
                sn  = fdot2(wn_[0], (h2){hA[0], hA[1]}, sn );
                sn1 = fdot2(wn_[1], (h2){hA[2], hA[3]}, sn1);
                sn  = fdot2(wn_[2], (h2){hA[4], hA[5]}, sn );
                sn1 = fdot2(wn_[3], (h2){hA[6], hA[7]}, sn1);
                sn  = fdot2(wn_[4], (h2){hB[0], hB[1]}, sn );
                sn1 = fdot2(wn_[5], (h2){hB[2], hB[3]}, sn1);
                sn  = fdot2(wn_[6], (h2){hB[4], hB[5]}, sn );
                sn1 = fdot2(wn_[7], (h2){hB[6], hB[7]}, sn1);
            }
            const float ghr = sr + sr1;
            const float ghz = sz + sz1;
            const float ghn = sn + sn1;

            const float r  = RCPF(1.0f + EXP2F(-(gxr + ghr)));
            const float zz = RCPF(1.0f + EXP2F(-(gxz + ghz)));
            const float nv = tanh_pre(gxn + r * ghn);
            const float hnew = nv + zz * (h_own - nv);
            h_own = hnew;
            h1w[(c * CHUNK + ls) * HD] = (_Float16)hnew;    // pure sink (attn reads)
        }
        afA = afAn;
        afB = afBn;
    }
    __syncthreads();

    // attention scratch overlays the (now dead) ring
    float* w_sh = reinterpret_cast<float*>(ring);          // 128 floats
    float* red  = reinterpret_cast<float*>(ring) + 128;    // 4 floats
    float* cvp  = reinterpret_cast<float*>(ring) + 136;    // 128 floats

    // ---- Attention per sequence (4 per block) ----
    // h1[t][0..15] = fwd (row t of sdf), h1[t][16..31] = bwd (row 127-t of sdb)
    for (int S = 0; S < 4; ++S) {
        const int sdf = (S >> 1) * 4 + (S & 1);
        const int sdb = sdf + 2;
        float hh[AD];
        {
            const f16x8* fp = (const f16x8*)(h1pool + sdf * SROW + tid * HD);
            const f16x8* bp = (const f16x8*)(h1pool + sdb * SROW + (TSTEPS - 1 - tid) * HD);
            const f16x8 f0 = fp[0], f1 = fp[1], b0v = bp[0], b1v = bp[1];
            #pragma unroll
            for (int e = 0; e < 8; ++e) {
                hh[e]      = (float)f0[e];
                hh[8 + e]  = (float)f1[e];
                hh[16 + e] = (float)b0v[e];
                hh[24 + e] = (float)b1v[e];
            }
        }
        float st = 0.0f;
        for (int i = 0; i < AD; ++i) {
            float a0 = ba[i], a1 = 0.f;
            const float* war = &Wa[i * AD];
            #pragma unroll
            for (int k = 0; k < AD; k += 2) {
                a0 += war[k] * hh[k];
                a1 += war[k + 1] * hh[k + 1];
            }
            st += tanh_pre(SC2 * (a0 + a1)) * ctxv[i];
        }
        // softmax over the 128 t's (2 waves)
        float mx = st;
        #pragma unroll
        for (int off = 32; off > 0; off >>= 1) mx = fmaxf(mx, __shfl_xor(mx, off));
        if (lane == 0) red[wv] = mx;
        __syncthreads();
        mx = fmaxf(red[0], red[1]);
        const float e = EXP2F(SC1 * (st - mx));
        float ss = e;
        #pragma unroll
        for (int off = 32; off > 0; off >>= 1) ss += __shfl_xor(ss, off);
        if (lane == 0) red[2 + wv] = ss;
        __syncthreads();
        const float Z = red[2] + red[3];
        w_sh[tid] = e * RCPF(Z);
        __syncthreads();

        // partial cv: 4 groups of 32 t's
        {
            const int g4 = tid >> 5, i4 = tid & 31;
            float acc = 0.0f;
            for (int k = 0; k < 32; ++k) {
                const int tt = g4 * 32 + k;
                const float hv = (i4 < HD)
                    ? (float)h1pool[sdf * SROW + tt * HD + i4]
                    : (float)h1pool[sdb * SROW + (TSTEPS - 1 - tt) * HD + (i4 - HD)];
                acc += w_sh[tt] * hv;
            }
            cvp[g4 * AD + i4] = acc;
        }
        __syncthreads();

        if (HAS_PROJ) {
            if (tid < HD) {
                float a = bm[tid];
                #pragma unroll
                for (int i = 0; i < AD; ++i)
                    a += Wm[tid * AD + i] *
                         (cvp[i] + cvp[AD + i] + cvp[2 * AD + i] + cvp[3 * AD + i]);
                out[(size_t)(blockIdx.x * 4 + S) * out_cols + tid] = a;
            }
        } else {
            if (tid < AD)
                out[(size_t)(blockIdx.x * 4 + S) * out_cols + tid] =
                    cvp[tid] + cvp[AD + tid] + cvp[2 * AD + tid] + cvp[3 * AD + tid];
        }
        __syncthreads();
    }
}

extern "C" void kernel_launch(void* const* d_in, const int* in_sizes, int n_in,
                              void* d_out, int out_size, void* d_ws, size_t ws_size,
                              hipStream_t stream) {
    const float* x     = (const float*)d_in[0];
    const float* Wih1f = (const float*)d_in[1];
    const float* Whh1f = (const float*)d_in[2];
    const float* bih1f = (const float*)d_in[3];
    const float* bhh1f = (const float*)d_in[4];
    const float* Wih1b = (const float*)d_in[5];
    const float* Whh1b = (const float*)d_in[6];
    const float* bih1b = (const float*)d_in[7];
    const float* bhh1b = (const float*)d_in[8];
    const float* Wih2f = (const float*)d_in[9];
    const float* Whh2f = (const float*)d_in[10];
    const float* bih2f = (const float*)d_in[11];
    const float* bhh2f = (const float*)d_in[12];
    const float* Wih2b = (const float*)d_in[13];
    const float* Whh2b = (const float*)d_in[14];
    const float* bih2b = (const float*)d_in[15];
    const float* bhh2b = (const float*)d_in[16];
    const float* Wa1   = (const float*)d_in[17];
    const float* ba1   = (const float*)d_in[18];
    const float* ctx1  = (const float*)d_in[19];
    const float* Wa2   = (const float*)d_in[20];
    const float* ba2   = (const float*)d_in[21];
    const float* ctx2  = (const float*)d_in[22];
    const float* Wm    = (const float*)d_in[23];
    const float* bm    = (const float*)d_in[24];

    float* flow = (float*)d_ws;          // [8192, 16]
    float* outp = (float*)d_out;         // [64, 32]

    // Stage 1: 8192 sequences, 4 per block
    gru_attn_kernel<25, true><<<2048, 128, 0, stream>>>(
        x, Wih1f, Whh1f, bih1f, bhh1f, Wih1b, Whh1b, bih1b, bhh1b,
        Wa1, ba1, ctx1, Wm, bm, flow, 16);

    // Stage 2: 64 sequences (input = flow viewed as [64, 128, 16]), 4 per block
    gru_attn_kernel<16, false><<<16, 128, 0, stream>>>(
        flow, Wih2f, Whh2f, bih2f, bhh2f, Wih2b, Whh2b, bih2b, bhh2b,
        Wa2, ba2, ctx2, nullptr, nullptr, outp, 32);
}